// Round 1
// baseline (1296.612 us; speedup 1.0000x reference)
//
#include <hip/hip_runtime.h>
#include <hip/hip_bf16.h>

// Problem constants
#define N_NODES 50000
#define N_EDGES 500000
#define IN_CH   128
#define D       256   // HEADS * OUT_CH
#define OUT_CH  64
#define HEADS   4

// ---------------------------------------------------------------------------
// Kernel E: init d_out with bias broadcast, zero softmax denominators S[4]
// ---------------------------------------------------------------------------
__global__ __launch_bounds__(256) void init_out_kernel(float* __restrict__ out,
                                                       const float* __restrict__ b_out,
                                                       double* __restrict__ S) {
    int i = blockIdx.x * 256 + threadIdx.x;
    if (i < N_NODES * OUT_CH) out[i] = b_out[i & 63];
    if (i < HEADS) S[i] = 0.0;
}

// ---------------------------------------------------------------------------
// Kernel A: Z_h = Wv_h @ Wout_h  (fold output projection into V projection)
// Z stored as [128][256] with column h*64+c == Z_h[:,c]
// ---------------------------------------------------------------------------
__global__ __launch_bounds__(256) void zbuild_kernel(const float* __restrict__ Wv,
                                                     const float* __restrict__ Wout,
                                                     float* __restrict__ Z) {
    int h = blockIdx.x;          // 4 blocks, one per head
    int tid = threadIdx.x;       // 256 threads
    __shared__ float wo[64 * 64];
    for (int i = tid; i < 64 * 64; i += 256) {
        int j = i >> 6, c = i & 63;
        wo[i] = Wout[(h * 64 + j) * OUT_CH + c];
    }
    __syncthreads();
    int c = tid & 63, i0 = tid >> 6;
    for (int i = i0; i < IN_CH; i += 4) {
        float s = 0.f;
        const float* wv = Wv + (size_t)i * D + h * 64;
        #pragma unroll 8
        for (int j = 0; j < 64; ++j) s += wv[j] * wo[j * 64 + c];
        Z[(size_t)i * D + h * 64 + c] = s;
    }
}

// ---------------------------------------------------------------------------
// Kernel B: fused GEMM  [50000x128] @ [128x768] -> Q | K | V'
// BM=BN=128, BK=32, 256 threads, 8x8 microtile.
// Column-block bn selects which weight matrix / output buffer.
// ---------------------------------------------------------------------------
__global__ __launch_bounds__(256) void gemm_qkv_kernel(const float* __restrict__ x,
                                                       const float* __restrict__ Wq,
                                                       const float* __restrict__ Wk,
                                                       const float* __restrict__ Z,
                                                       float* __restrict__ Q,
                                                       float* __restrict__ K,
                                                       float* __restrict__ V) {
    __shared__ float As[32][128];   // transposed: As[k][m]
    __shared__ float Bs[32][128];   // natural:    Bs[k][n]

    const int bm = blockIdx.x;
    const int bn = blockIdx.y;                 // 0..5 (6 col-blocks of 128)
    const float* W = (bn < 2) ? Wq : (bn < 4) ? Wk : Z;
    float*       O = (bn < 2) ? Q  : (bn < 4) ? K  : V;
    const int colbase = (bn & 1) * 128;
    const int m0 = bm * 128;
    const int tid = threadIdx.x;
    const int tx = tid & 15, ty = tid >> 4;

    float acc[8][8];
    #pragma unroll
    for (int i = 0; i < 8; ++i)
        #pragma unroll
        for (int j = 0; j < 8; ++j) acc[i][j] = 0.f;

    for (int kt = 0; kt < 4; ++kt) {
        const int k0 = kt * 32;
        // stage A tile (transpose into As[k][m])
        #pragma unroll
        for (int r = 0; r < 4; ++r) {
            int f = tid + r * 256;          // 0..1023
            int m = f >> 3, k4 = (f & 7) << 2;
            float4 v = make_float4(0.f, 0.f, 0.f, 0.f);
            if (m0 + m < N_NODES)
                v = *(const float4*)(x + (size_t)(m0 + m) * IN_CH + k0 + k4);
            As[k4 + 0][m] = v.x; As[k4 + 1][m] = v.y;
            As[k4 + 2][m] = v.z; As[k4 + 3][m] = v.w;
        }
        // stage B tile (natural layout)
        #pragma unroll
        for (int r = 0; r < 4; ++r) {
            int f = tid + r * 256;
            int kb = f >> 5, n4 = (f & 31) << 2;
            *(float4*)&Bs[kb][n4] = *(const float4*)(W + (size_t)(k0 + kb) * D + colbase + n4);
        }
        __syncthreads();
        #pragma unroll
        for (int kk = 0; kk < 32; ++kk) {
            float a[8], b[8];
            *(float4*)(a)     = *(float4*)&As[kk][ty * 8];
            *(float4*)(a + 4) = *(float4*)&As[kk][ty * 8 + 4];
            *(float4*)(b)     = *(float4*)&Bs[kk][tx * 8];
            *(float4*)(b + 4) = *(float4*)&Bs[kk][tx * 8 + 4];
            #pragma unroll
            for (int i = 0; i < 8; ++i)
                #pragma unroll
                for (int j = 0; j < 8; ++j)
                    acc[i][j] += a[i] * b[j];
        }
        __syncthreads();
    }
    // store
    #pragma unroll
    for (int i = 0; i < 8; ++i) {
        int m = m0 + ty * 8 + i;
        if (m < N_NODES) {
            float* dst = O + (size_t)m * D + colbase + tx * 8;
            *(float4*)(dst)     = *(float4*)&acc[i][0];
            *(float4*)(dst + 4) = *(float4*)&acc[i][4];
        }
    }
}

// ---------------------------------------------------------------------------
// Kernel C: per-edge logits -> p = exp(leaky(q.k/8 + ew*We)); accumulate S[h]
// 4 lanes per edge (one per head); float4 dot over 64 channels.
// ---------------------------------------------------------------------------
__global__ __launch_bounds__(256) void edge_logits_kernel(const float* __restrict__ Q,
                                                          const float* __restrict__ K,
                                                          const int* __restrict__ ei,
                                                          const float* __restrict__ ew,
                                                          const float* __restrict__ We,
                                                          float* __restrict__ P,
                                                          double* __restrict__ S) {
    const int tid = threadIdx.x;
    const long long gid = (long long)blockIdx.x * 256 + tid;
    const int h = (int)(gid & 3);
    const long long e = gid >> 2;
    float p = 0.f;
    if (e < N_EDGES) {
        const int s = ei[e];
        const int t = ei[N_EDGES + e];
        const float4* q = (const float4*)(Q + (size_t)t * D + h * 64);
        const float4* k = (const float4*)(K + (size_t)s * D + h * 64);
        float sum = 0.f;
        #pragma unroll
        for (int i = 0; i < 16; ++i) {
            float4 a = q[i], b = k[i];
            sum += a.x * b.x + a.y * b.y + a.z * b.z + a.w * b.w;
        }
        float l = sum * 0.125f + ew[e] * We[h];
        l = (l > 0.f) ? l : 0.2f * l;       // leaky_relu(0.2)
        p = __expf(l);                       // logits bounded ~[-2,6]: safe w/o max-sub
        P[e * 4 + h] = p;
    }
    // per-head reduction across the wave (lanes with same lane&3)
    float sum = p;
    sum += __shfl_xor(sum, 4, 64);
    sum += __shfl_xor(sum, 8, 64);
    sum += __shfl_xor(sum, 16, 64);
    sum += __shfl_xor(sum, 32, 64);
    __shared__ float sblk[HEADS];
    if (tid < HEADS) sblk[tid] = 0.f;
    __syncthreads();
    if ((tid & 63) < HEADS) atomicAdd(&sblk[tid & 3], sum);
    __syncthreads();
    if (tid < HEADS) atomicAdd(&S[tid], (double)sblk[tid]);
}

// ---------------------------------------------------------------------------
// Kernel C2: P[e,h] *= 1/S[h]
// ---------------------------------------------------------------------------
__global__ __launch_bounds__(256) void scale_p_kernel(float* __restrict__ P,
                                                      const double* __restrict__ S) {
    int i = blockIdx.x * 256 + threadIdx.x;
    if (i < N_EDGES * HEADS) {
        float inv = (float)(1.0 / S[i & 3]);
        P[i] *= inv;
    }
}

// ---------------------------------------------------------------------------
// Kernel D: out[tgt] += sum_h w[e,h] * V'_h[src]   (64 ch per node)
// 16 lanes per edge, each handles a float4 of the 64 output channels.
// ---------------------------------------------------------------------------
__global__ __launch_bounds__(256) void aggregate_kernel(const float* __restrict__ V,
                                                        const float* __restrict__ P,
                                                        const int* __restrict__ ei,
                                                        float* __restrict__ out) {
    const int tid = threadIdx.x;
    const long long gid = (long long)blockIdx.x * 256 + tid;
    const int j = (int)(gid & 15);
    const long long e = gid >> 4;
    if (e >= N_EDGES) return;
    const int s = ei[e];
    const int t = ei[N_EDGES + e];
    const float4 p = *(const float4*)(P + e * 4);
    const float4* v = (const float4*)(V + (size_t)s * D);   // 64 float4 per row
    const float4 v0 = v[j], v1 = v[j + 16], v2 = v[j + 32], v3 = v[j + 48];
    float4 a;
    a.x = p.x * v0.x + p.y * v1.x + p.z * v2.x + p.w * v3.x;
    a.y = p.x * v0.y + p.y * v1.y + p.z * v2.y + p.w * v3.y;
    a.z = p.x * v0.z + p.y * v1.z + p.z * v2.z + p.w * v3.z;
    a.w = p.x * v0.w + p.y * v1.w + p.z * v2.w + p.w * v3.w;
    float* dst = out + (size_t)t * OUT_CH + j * 4;
    atomicAdd(dst + 0, a.x);
    atomicAdd(dst + 1, a.y);
    atomicAdd(dst + 2, a.z);
    atomicAdd(dst + 3, a.w);
}

// ---------------------------------------------------------------------------
// Launch
// ---------------------------------------------------------------------------
extern "C" void kernel_launch(void* const* d_in, const int* in_sizes, int n_in,
                              void* d_out, int out_size, void* d_ws, size_t ws_size,
                              hipStream_t stream) {
    const float* x     = (const float*)d_in[0];
    const int*   ei    = (const int*)d_in[1];   // [2, E] int32 (JAX demotes int64)
    const float* ew    = (const float*)d_in[2];
    const float* Wq    = (const float*)d_in[3];
    const float* Wk    = (const float*)d_in[4];
    const float* Wv    = (const float*)d_in[5];
    const float* We    = (const float*)d_in[6];
    const float* Wout  = (const float*)d_in[7];
    const float* b_out = (const float*)d_in[8];
    float* out = (float*)d_out;

    // workspace layout (~162 MB)
    float*  Q = (float*)d_ws;                       // 50000*256
    float*  K = Q + (size_t)N_NODES * D;            // 50000*256
    float*  V = K + (size_t)N_NODES * D;            // 50000*256
    float*  P = V + (size_t)N_NODES * D;            // 500000*4
    double* S = (double*)(P + (size_t)N_EDGES * HEADS);  // 4 doubles (8B aligned)
    float*  Z = (float*)(S + HEADS);                // 128*256

    init_out_kernel<<<(N_NODES * OUT_CH + 255) / 256, 256, 0, stream>>>(out, b_out, S);
    zbuild_kernel<<<HEADS, 256, 0, stream>>>(Wv, Wout, Z);
    gemm_qkv_kernel<<<dim3((N_NODES + 127) / 128, 6), 256, 0, stream>>>(x, Wq, Wk, Z, Q, K, V);
    edge_logits_kernel<<<(N_EDGES * HEADS + 255) / 256, 256, 0, stream>>>(Q, K, ei, ew, We, P, S);
    scale_p_kernel<<<(N_EDGES * HEADS + 255) / 256, 256, 0, stream>>>(P, S);
    aggregate_kernel<<<(N_EDGES * 16 + 255) / 256, 256, 0, stream>>>(V, P, ei, out);
}

// Round 2
// 1267.735 us; speedup vs baseline: 1.0228x; 1.0228x over previous
//
#include <hip/hip_runtime.h>
#include <hip/hip_bf16.h>

// Problem constants
#define N_NODES 50000
#define N_EDGES 500000
#define IN_CH   128
#define D       256   // HEADS * OUT_CH
#define OUT_CH  64
#define HEADS   4

// ---------------------------------------------------------------------------
// init: d_out = bias broadcast, S[4]=0, cnt[]=0 (for histogram)
// ---------------------------------------------------------------------------
__global__ __launch_bounds__(256) void init_out_kernel(float* __restrict__ out,
                                                       const float* __restrict__ b_out,
                                                       double* __restrict__ S,
                                                       int* __restrict__ cnt) {
    int i = blockIdx.x * 256 + threadIdx.x;
    if (i < N_NODES * OUT_CH) out[i] = b_out[i & 63];
    if (i < HEADS) S[i] = 0.0;
    if (i <= N_NODES) cnt[i] = 0;
}

// ---------------------------------------------------------------------------
// Z_h = Wv_h @ Wout_h  (fold output projection into V projection)
// ---------------------------------------------------------------------------
__global__ __launch_bounds__(256) void zbuild_kernel(const float* __restrict__ Wv,
                                                     const float* __restrict__ Wout,
                                                     float* __restrict__ Z) {
    int h = blockIdx.x;
    int tid = threadIdx.x;
    __shared__ float wo[64 * 64];
    for (int i = tid; i < 64 * 64; i += 256) {
        int j = i >> 6, c = i & 63;
        wo[i] = Wout[(h * 64 + j) * OUT_CH + c];
    }
    __syncthreads();
    int c = tid & 63, i0 = tid >> 6;
    for (int i = i0; i < IN_CH; i += 4) {
        float s = 0.f;
        const float* wv = Wv + (size_t)i * D + h * 64;
        #pragma unroll 8
        for (int j = 0; j < 64; ++j) s += wv[j] * wo[j * 64 + c];
        Z[(size_t)i * D + h * 64 + c] = s;
    }
}

// ---------------------------------------------------------------------------
// fused GEMM  [50000x128] @ [128x768] -> Q | K | V'
// ---------------------------------------------------------------------------
__global__ __launch_bounds__(256) void gemm_qkv_kernel(const float* __restrict__ x,
                                                       const float* __restrict__ Wq,
                                                       const float* __restrict__ Wk,
                                                       const float* __restrict__ Z,
                                                       float* __restrict__ Q,
                                                       float* __restrict__ K,
                                                       float* __restrict__ V) {
    __shared__ float As[32][128];
    __shared__ float Bs[32][128];

    const int bm = blockIdx.x;
    const int bn = blockIdx.y;
    const float* W = (bn < 2) ? Wq : (bn < 4) ? Wk : Z;
    float*       O = (bn < 2) ? Q  : (bn < 4) ? K  : V;
    const int colbase = (bn & 1) * 128;
    const int m0 = bm * 128;
    const int tid = threadIdx.x;
    const int tx = tid & 15, ty = tid >> 4;

    float acc[8][8];
    #pragma unroll
    for (int i = 0; i < 8; ++i)
        #pragma unroll
        for (int j = 0; j < 8; ++j) acc[i][j] = 0.f;

    for (int kt = 0; kt < 4; ++kt) {
        const int k0 = kt * 32;
        #pragma unroll
        for (int r = 0; r < 4; ++r) {
            int f = tid + r * 256;
            int m = f >> 3, k4 = (f & 7) << 2;
            float4 v = make_float4(0.f, 0.f, 0.f, 0.f);
            if (m0 + m < N_NODES)
                v = *(const float4*)(x + (size_t)(m0 + m) * IN_CH + k0 + k4);
            As[k4 + 0][m] = v.x; As[k4 + 1][m] = v.y;
            As[k4 + 2][m] = v.z; As[k4 + 3][m] = v.w;
        }
        #pragma unroll
        for (int r = 0; r < 4; ++r) {
            int f = tid + r * 256;
            int kb = f >> 5, n4 = (f & 31) << 2;
            *(float4*)&Bs[kb][n4] = *(const float4*)(W + (size_t)(k0 + kb) * D + colbase + n4);
        }
        __syncthreads();
        #pragma unroll
        for (int kk = 0; kk < 32; ++kk) {
            float a[8], b[8];
            *(float4*)(a)     = *(float4*)&As[kk][ty * 8];
            *(float4*)(a + 4) = *(float4*)&As[kk][ty * 8 + 4];
            *(float4*)(b)     = *(float4*)&Bs[kk][tx * 8];
            *(float4*)(b + 4) = *(float4*)&Bs[kk][tx * 8 + 4];
            #pragma unroll
            for (int i = 0; i < 8; ++i)
                #pragma unroll
                for (int j = 0; j < 8; ++j)
                    acc[i][j] += a[i] * b[j];
        }
        __syncthreads();
    }
    #pragma unroll
    for (int i = 0; i < 8; ++i) {
        int m = m0 + ty * 8 + i;
        if (m < N_NODES) {
            float* dst = O + (size_t)m * D + colbase + tx * 8;
            *(float4*)(dst)     = *(float4*)&acc[i][0];
            *(float4*)(dst + 4) = *(float4*)&acc[i][4];
        }
    }
}

// ---------------------------------------------------------------------------
// counting sort by src:  histogram -> exclusive scan -> scatter
// ---------------------------------------------------------------------------
__global__ __launch_bounds__(256) void hist_kernel(const int* __restrict__ ei,
                                                   int* __restrict__ cnt) {
    int e = blockIdx.x * 256 + threadIdx.x;
    if (e < N_EDGES) atomicAdd(&cnt[ei[e]], 1);
}

// single-block exclusive scan over cnt[0..N_NODES), 256 thr, 4 elems/thr/chunk
__global__ __launch_bounds__(256) void scan_kernel(int* __restrict__ cnt) {
    __shared__ int wsum[4];
    __shared__ int carry_s;
    const int tid = threadIdx.x, lane = tid & 63, wid = tid >> 6;
    if (tid == 0) carry_s = 0;
    __syncthreads();
    for (int base = 0; base < N_NODES; base += 1024) {
        int v[4];
        const int idx0 = base + tid * 4;
        #pragma unroll
        for (int i = 0; i < 4; ++i) {
            int idx = idx0 + i;
            v[i] = (idx < N_NODES) ? cnt[idx] : 0;
        }
        int tsum = v[0] + v[1] + v[2] + v[3];
        int x = tsum;
        #pragma unroll
        for (int d = 1; d < 64; d <<= 1) {
            int y = __shfl_up(x, d, 64);
            if (lane >= d) x += y;
        }
        if (lane == 63) wsum[wid] = x;
        __syncthreads();
        int woff = 0;
        for (int w = 0; w < wid; ++w) woff += wsum[w];
        int carry = carry_s;
        int total = wsum[0] + wsum[1] + wsum[2] + wsum[3];
        __syncthreads();
        int excl = carry + woff + x - tsum;
        #pragma unroll
        for (int i = 0; i < 4; ++i) {
            int idx = idx0 + i;
            if (idx < N_NODES) cnt[idx] = excl;
            excl += v[i];
        }
        if (tid == 0) carry_s = carry + total;
        // next iteration's first __syncthreads separates this write from reads
    }
}

__global__ __launch_bounds__(256) void scatter_kernel(const int* __restrict__ ei,
                                                      const float* __restrict__ ew,
                                                      int* __restrict__ cnt,
                                                      int* __restrict__ es,
                                                      int* __restrict__ et,
                                                      float* __restrict__ ewp) {
    int e = blockIdx.x * 256 + threadIdx.x;
    if (e >= N_EDGES) return;
    int s = ei[e], t = ei[N_EDGES + e];
    int pos = atomicAdd(&cnt[s], 1);
    es[pos] = s;
    et[pos] = t;
    ewp[pos] = ew[e];
}

// ---------------------------------------------------------------------------
// edge logits on src-sorted edges: 16 lanes/edge, contiguous float4 reads.
// p = exp(leaky(q.k/8 + ew*We)); accumulate S[h] (double).
// ---------------------------------------------------------------------------
__global__ __launch_bounds__(256) void edge_logits_kernel(const float* __restrict__ Q,
                                                          const float* __restrict__ K,
                                                          const int* __restrict__ es,
                                                          const int* __restrict__ et,
                                                          const float* __restrict__ ewp,
                                                          const float* __restrict__ We,
                                                          float* __restrict__ P,
                                                          double* __restrict__ S) {
    const int tid = threadIdx.x;
    const long long gid = (long long)blockIdx.x * 256 + tid;
    const int j = (int)(gid & 15);
    const long long e = gid >> 4;
    const bool valid = (e < N_EDGES);
    float dot[4] = {0.f, 0.f, 0.f, 0.f};
    if (valid) {
        const int s = es[e];
        const int t = et[e];
        const float4* q = (const float4*)(Q + (size_t)t * D);
        const float4* k = (const float4*)(K + (size_t)s * D);
        #pragma unroll
        for (int i = 0; i < 4; ++i) {       // i = head
            float4 a = q[i * 16 + j];
            float4 b = k[i * 16 + j];
            dot[i] = a.x * b.x + a.y * b.y + a.z * b.z + a.w * b.w;
        }
    }
    #pragma unroll
    for (int m = 1; m < 16; m <<= 1) {
        #pragma unroll
        for (int i = 0; i < 4; ++i) dot[i] += __shfl_xor(dot[i], m, 64);
    }
    float p[4] = {0.f, 0.f, 0.f, 0.f};
    if (valid && j == 0) {
        float w = ewp[e];
        #pragma unroll
        for (int h = 0; h < 4; ++h) {
            float l = dot[h] * 0.125f + w * We[h];
            l = (l > 0.f) ? l : 0.2f * l;
            p[h] = __expf(l);
        }
        *(float4*)(P + e * 4) = make_float4(p[0], p[1], p[2], p[3]);
    }
    __shared__ float sblk[HEADS];
    if (tid < HEADS) sblk[tid] = 0.f;
    __syncthreads();
    if (valid && j == 0) {
        #pragma unroll
        for (int h = 0; h < 4; ++h) atomicAdd(&sblk[h], p[h]);
    }
    __syncthreads();
    if (tid < HEADS) atomicAdd(&S[tid], (double)sblk[tid]);
}

// ---------------------------------------------------------------------------
// P[e,h] *= 1/S[h]
// ---------------------------------------------------------------------------
__global__ __launch_bounds__(256) void scale_p_kernel(float* __restrict__ P,
                                                      const double* __restrict__ S) {
    int i = blockIdx.x * 256 + threadIdx.x;
    if (i < N_EDGES * HEADS) {
        float inv = (float)(1.0 / S[i & 3]);
        P[i] *= inv;
    }
}

// ---------------------------------------------------------------------------
// aggregate on src-sorted edges: out[tgt] += sum_h w[e,h] * V'_h[src]
// ---------------------------------------------------------------------------
__global__ __launch_bounds__(256) void aggregate_kernel(const float* __restrict__ V,
                                                        const float* __restrict__ P,
                                                        const int* __restrict__ es,
                                                        const int* __restrict__ et,
                                                        float* __restrict__ out) {
    const int tid = threadIdx.x;
    const long long gid = (long long)blockIdx.x * 256 + tid;
    const int j = (int)(gid & 15);
    const long long e = gid >> 4;
    if (e >= N_EDGES) return;
    const int s = es[e];
    const int t = et[e];
    const float4 p = *(const float4*)(P + e * 4);
    const float4* v = (const float4*)(V + (size_t)s * D);
    const float4 v0 = v[j], v1 = v[j + 16], v2 = v[j + 32], v3 = v[j + 48];
    float4 a;
    a.x = p.x * v0.x + p.y * v1.x + p.z * v2.x + p.w * v3.x;
    a.y = p.x * v0.y + p.y * v1.y + p.z * v2.y + p.w * v3.y;
    a.z = p.x * v0.z + p.y * v1.z + p.z * v2.z + p.w * v3.z;
    a.w = p.x * v0.w + p.y * v1.w + p.z * v2.w + p.w * v3.w;
    float* dst = out + (size_t)t * OUT_CH + j * 4;
    atomicAdd(dst + 0, a.x);
    atomicAdd(dst + 1, a.y);
    atomicAdd(dst + 2, a.z);
    atomicAdd(dst + 3, a.w);
}

// ---------------------------------------------------------------------------
// Launch
// ---------------------------------------------------------------------------
extern "C" void kernel_launch(void* const* d_in, const int* in_sizes, int n_in,
                              void* d_out, int out_size, void* d_ws, size_t ws_size,
                              hipStream_t stream) {
    const float* x     = (const float*)d_in[0];
    const int*   ei    = (const int*)d_in[1];   // [2, E] int32
    const float* ew    = (const float*)d_in[2];
    const float* Wq    = (const float*)d_in[3];
    const float* Wk    = (const float*)d_in[4];
    const float* Wv    = (const float*)d_in[5];
    const float* We    = (const float*)d_in[6];
    const float* Wout  = (const float*)d_in[7];
    const float* b_out = (const float*)d_in[8];
    float* out = (float*)d_out;

    // workspace layout (~168 MB)
    float*  Q   = (float*)d_ws;                            // 50000*256
    float*  K   = Q + (size_t)N_NODES * D;                 // 50000*256
    float*  V   = K + (size_t)N_NODES * D;                 // 50000*256
    float*  P   = V + (size_t)N_NODES * D;                 // 500000*4
    double* S   = (double*)(P + (size_t)N_EDGES * HEADS);  // 4 doubles
    float*  Z   = (float*)(S + HEADS);                     // 128*256
    int*    es  = (int*)(Z + IN_CH * D);                   // 500000
    int*    et  = es + N_EDGES;                            // 500000
    float*  ewp = (float*)(et + N_EDGES);                  // 500000
    int*    cnt = (int*)(ewp + N_EDGES);                   // 50001

    init_out_kernel<<<(N_NODES * OUT_CH + 255) / 256, 256, 0, stream>>>(out, b_out, S, cnt);
    zbuild_kernel<<<HEADS, 256, 0, stream>>>(Wv, Wout, Z);
    gemm_qkv_kernel<<<dim3((N_NODES + 127) / 128, 6), 256, 0, stream>>>(x, Wq, Wk, Z, Q, K, V);
    hist_kernel<<<(N_EDGES + 255) / 256, 256, 0, stream>>>(ei, cnt);
    scan_kernel<<<1, 256, 0, stream>>>(cnt);
    scatter_kernel<<<(N_EDGES + 255) / 256, 256, 0, stream>>>(ei, ew, cnt, es, et, ewp);
    edge_logits_kernel<<<(int)(((long long)N_EDGES * 16 + 255) / 256), 256, 0, stream>>>(Q, K, es, et, ewp, We, P, S);
    scale_p_kernel<<<(N_EDGES * HEADS + 255) / 256, 256, 0, stream>>>(P, S);
    aggregate_kernel<<<(int)(((long long)N_EDGES * 16 + 255) / 256), 256, 0, stream>>>(V, P, es, et, out);
}

// Round 3
// 657.747 us; speedup vs baseline: 1.9713x; 1.9274x over previous
//
#include <hip/hip_runtime.h>
#include <hip/hip_bf16.h>

// Problem constants
#define N_NODES 50000
#define N_EDGES 500000
#define IN_CH   128
#define D       256   // HEADS * OUT_CH (V' width)
#define UDIM    512   // HEADS * 128    (u width)
#define OUT_CH  64
#define HEADS   4
#define NC      49    // scan chunks of 1024: ceil(50000/1024)

// ---------------------------------------------------------------------------
// init: zero histogram counters and softmax denominators
// ---------------------------------------------------------------------------
__global__ __launch_bounds__(256) void init_kernel(int* __restrict__ cnt,
                                                   double* __restrict__ S) {
    int i = blockIdx.x * 256 + threadIdx.x;
    if (i < N_NODES) cnt[i] = 0;
    if (i < HEADS) S[i] = 0.0;
}

// ---------------------------------------------------------------------------
// M[i][h*128+j] = sum_c Wq[i][h*64+c] * Wk[j][h*64+c]   (one block per head)
// ---------------------------------------------------------------------------
__global__ __launch_bounds__(256) void mbuild_kernel(const float* __restrict__ Wq,
                                                     const float* __restrict__ Wk,
                                                     float* __restrict__ M) {
    const int h = blockIdx.x;
    const int tid = threadIdx.x;
    __shared__ float ks[128][64];   // Wk_h : 32 KB
    for (int i = tid; i < 128 * 64; i += 256) {
        int r = i >> 6, c = i & 63;
        ks[r][c] = Wk[(size_t)r * D + h * 64 + c];
    }
    __syncthreads();
    const int i = tid >> 1;            // row 0..127
    const int j0 = (tid & 1) * 64;     // col half
    float q[64];
    #pragma unroll 16
    for (int c = 0; c < 64; ++c) q[c] = Wq[(size_t)i * D + h * 64 + c];
    for (int jj = 0; jj < 64; ++jj) {
        int j = j0 + jj;
        float s = 0.f;
        #pragma unroll 16
        for (int c = 0; c < 64; ++c) s += q[c] * ks[j][c];
        M[(size_t)i * UDIM + h * 128 + j] = s;
    }
}

// ---------------------------------------------------------------------------
// Z_h = Wv_h @ Wout_h  (fold output projection into V projection)
// ---------------------------------------------------------------------------
__global__ __launch_bounds__(256) void zbuild_kernel(const float* __restrict__ Wv,
                                                     const float* __restrict__ Wout,
                                                     float* __restrict__ Z) {
    int h = blockIdx.x;
    int tid = threadIdx.x;
    __shared__ float wo[64 * 64];
    for (int i = tid; i < 64 * 64; i += 256) {
        int j = i >> 6, c = i & 63;
        wo[i] = Wout[(h * 64 + j) * OUT_CH + c];
    }
    __syncthreads();
    int c = tid & 63, i0 = tid >> 6;
    for (int i = i0; i < IN_CH; i += 4) {
        float s = 0.f;
        const float* wv = Wv + (size_t)i * D + h * 64;
        #pragma unroll 8
        for (int j = 0; j < 64; ++j) s += wv[j] * wo[j * 64 + c];
        Z[(size_t)i * D + h * 64 + c] = s;
    }
}

// ---------------------------------------------------------------------------
// fused GEMM  [50000x128] @ [M | Z] -> u [50000x512] | Vp [50000x256]
// BM=BN=128, BK=32, 256 threads, 8x8 microtile with split halves
// (cols tx*4 and 64+tx*4) so LDS reads are 16B-contiguous across 16 lanes.
// ---------------------------------------------------------------------------
__global__ __launch_bounds__(256) void gemm_kernel(const float* __restrict__ x,
                                                   const float* __restrict__ M,
                                                   const float* __restrict__ Z,
                                                   float* __restrict__ u,
                                                   float* __restrict__ Vp) {
    __shared__ float As[32][128];
    __shared__ float Bs[32][128];

    const int bm = blockIdx.x;
    const int bn = blockIdx.y;          // 0..5
    const float* W;
    float* O;
    int wstride, ostride, colbase;
    if (bn < 4) { W = M; wstride = UDIM; O = u;  ostride = UDIM; colbase = bn * 128; }
    else        { W = Z; wstride = D;    O = Vp; ostride = D;    colbase = (bn - 4) * 128; }
    const int m0 = bm * 128;
    const int tid = threadIdx.x;
    const int tx = tid & 15, ty = tid >> 4;

    float acc[8][8];
    #pragma unroll
    for (int i = 0; i < 8; ++i)
        #pragma unroll
        for (int j = 0; j < 8; ++j) acc[i][j] = 0.f;

    for (int kt = 0; kt < 4; ++kt) {
        const int k0 = kt * 32;
        #pragma unroll
        for (int r = 0; r < 4; ++r) {
            int f = tid + r * 256;
            int m = f >> 3, k4 = (f & 7) << 2;
            float4 v = make_float4(0.f, 0.f, 0.f, 0.f);
            if (m0 + m < N_NODES)
                v = *(const float4*)(x + (size_t)(m0 + m) * IN_CH + k0 + k4);
            As[k4 + 0][m] = v.x; As[k4 + 1][m] = v.y;
            As[k4 + 2][m] = v.z; As[k4 + 3][m] = v.w;
        }
        #pragma unroll
        for (int r = 0; r < 4; ++r) {
            int f = tid + r * 256;
            int kb = f >> 5, n4 = (f & 31) << 2;
            *(float4*)&Bs[kb][n4] = *(const float4*)(W + (size_t)(k0 + kb) * wstride + colbase + n4);
        }
        __syncthreads();
        #pragma unroll
        for (int kk = 0; kk < 32; ++kk) {
            float a[8], b[8];
            *(float4*)(a)     = *(float4*)&As[kk][ty * 4];
            *(float4*)(a + 4) = *(float4*)&As[kk][64 + ty * 4];
            *(float4*)(b)     = *(float4*)&Bs[kk][tx * 4];
            *(float4*)(b + 4) = *(float4*)&Bs[kk][64 + tx * 4];
            #pragma unroll
            for (int i = 0; i < 8; ++i)
                #pragma unroll
                for (int j = 0; j < 8; ++j)
                    acc[i][j] += a[i] * b[j];
        }
        __syncthreads();
    }
    #pragma unroll
    for (int i = 0; i < 8; ++i) {
        int row = (i < 4) ? (ty * 4 + i) : (64 + ty * 4 + (i - 4));
        int m = m0 + row;
        if (m < N_NODES) {
            float* dst = O + (size_t)m * ostride + colbase;
            *(float4*)(dst + tx * 4)      = *(float4*)&acc[i][0];
            *(float4*)(dst + 64 + tx * 4) = *(float4*)&acc[i][4];
        }
    }
}

// ---------------------------------------------------------------------------
// counting sort by tgt: histogram -> 3-phase scan -> scatter payload {src,w}
// ---------------------------------------------------------------------------
__global__ __launch_bounds__(256) void hist_kernel(const int* __restrict__ ei,
                                                   int* __restrict__ cnt) {
    int e = blockIdx.x * 256 + threadIdx.x;
    if (e < N_EDGES) atomicAdd(&cnt[ei[N_EDGES + e]], 1);
}

__global__ __launch_bounds__(256) void scan_reduce_kernel(const int* __restrict__ cnt,
                                                          int* __restrict__ csum) {
    const int b = blockIdx.x, tid = threadIdx.x;
    const int lane = tid & 63, wid = tid >> 6;
    int s = 0;
    int idx0 = b * 1024 + tid * 4;
    #pragma unroll
    for (int i = 0; i < 4; ++i) {
        int idx = idx0 + i;
        if (idx < N_NODES) s += cnt[idx];
    }
    #pragma unroll
    for (int m = 1; m < 64; m <<= 1) s += __shfl_xor(s, m, 64);
    __shared__ int w[4];
    if (lane == 0) w[wid] = s;
    __syncthreads();
    if (tid == 0) csum[b] = w[0] + w[1] + w[2] + w[3];
}

__global__ __launch_bounds__(64) void scan_top_kernel(int* __restrict__ csum) {
    int lane = threadIdx.x;
    int v = (lane < NC) ? csum[lane] : 0;
    int x = v;
    #pragma unroll
    for (int d = 1; d < 64; d <<= 1) {
        int y = __shfl_up(x, d, 64);
        if (lane >= d) x += y;
    }
    if (lane < NC) csum[lane] = x - v;   // exclusive
}

__global__ __launch_bounds__(256) void scan_chunks_kernel(int* __restrict__ cnt,
                                                          const int* __restrict__ csum,
                                                          int* __restrict__ rp) {
    const int b = blockIdx.x, tid = threadIdx.x;
    const int lane = tid & 63, wid = tid >> 6;
    __shared__ int wsum[4];
    int v[4];
    const int idx0 = b * 1024 + tid * 4;
    #pragma unroll
    for (int i = 0; i < 4; ++i) {
        int idx = idx0 + i;
        v[i] = (idx < N_NODES) ? cnt[idx] : 0;
    }
    int tsum = v[0] + v[1] + v[2] + v[3];
    int x = tsum;
    #pragma unroll
    for (int d = 1; d < 64; d <<= 1) {
        int y = __shfl_up(x, d, 64);
        if (lane >= d) x += y;
    }
    if (lane == 63) wsum[wid] = x;
    __syncthreads();
    int woff = 0;
    for (int w = 0; w < wid; ++w) woff += wsum[w];
    int excl = csum[b] + woff + x - tsum;
    #pragma unroll
    for (int i = 0; i < 4; ++i) {
        int idx = idx0 + i;
        if (idx < N_NODES) { rp[idx] = excl; cnt[idx] = excl; }
        excl += v[i];
    }
}

__global__ __launch_bounds__(256) void scatter_kernel(const int* __restrict__ ei,
                                                      const float* __restrict__ ew,
                                                      int* __restrict__ cnt,
                                                      int2* __restrict__ payload) {
    int e = blockIdx.x * 256 + threadIdx.x;
    if (e >= N_EDGES) return;
    int s = ei[e], t = ei[N_EDGES + e];
    int pos = atomicAdd(&cnt[t], 1);
    payload[pos] = make_int2(s, __float_as_int(ew[e]));
}

// ---------------------------------------------------------------------------
// logits: per-node (16 lanes/node). u[t] hoisted to registers; per edge
// gather x_src (512 B), dot via shfl(16), p = exp(leaky(...)), write P,
// accumulate S (double).
// ---------------------------------------------------------------------------
__global__ __launch_bounds__(256) void logits_kernel(const float* __restrict__ u,
                                                     const float* __restrict__ x,
                                                     const int* __restrict__ rp,
                                                     const int* __restrict__ cnt,
                                                     const int2* __restrict__ payload,
                                                     const float* __restrict__ We,
                                                     float* __restrict__ P,
                                                     double* __restrict__ S) {
    const int tid = threadIdx.x;
    const int j = tid & 15;
    const int node = blockIdx.x * 16 + (tid >> 4);
    const float4 we = *(const float4*)We;

    // hoist u[node] fragment: per head, floats [h*128 + j*8 .. +7]
    const float4* ur = (const float4*)(u + (size_t)node * UDIM);
    float4 ua[4], ub[4];
    #pragma unroll
    for (int h = 0; h < 4; ++h) {
        ua[h] = ur[h * 32 + j * 2];
        ub[h] = ur[h * 32 + j * 2 + 1];
    }

    float sacc0 = 0.f, sacc1 = 0.f, sacc2 = 0.f, sacc3 = 0.f;
    const int start = rp[node];
    const int end = cnt[node];
    for (int e = start; e < end; ++e) {
        int2 pl = payload[e];
        const int s = pl.x;
        const float w = __int_as_float(pl.y);
        const float4* xr = (const float4*)(x + (size_t)s * IN_CH);
        float4 xa = xr[j * 2], xb = xr[j * 2 + 1];
        float d[4];
        #pragma unroll
        for (int h = 0; h < 4; ++h) {
            d[h] = ua[h].x * xa.x + ua[h].y * xa.y + ua[h].z * xa.z + ua[h].w * xa.w
                 + ub[h].x * xb.x + ub[h].y * xb.y + ub[h].z * xb.z + ub[h].w * xb.w;
        }
        #pragma unroll
        for (int m = 1; m < 16; m <<= 1) {
            #pragma unroll
            for (int h = 0; h < 4; ++h) d[h] += __shfl_xor(d[h], m, 16);
        }
        float p[4];
        const float wev[4] = {we.x, we.y, we.z, we.w};
        #pragma unroll
        for (int h = 0; h < 4; ++h) {
            float l = d[h] * 0.125f + w * wev[h];
            l = (l > 0.f) ? l : 0.2f * l;
            p[h] = __expf(l);
        }
        if (j == 0) {
            *(float4*)(P + (size_t)e * 4) = make_float4(p[0], p[1], p[2], p[3]);
            sacc0 += p[0]; sacc1 += p[1]; sacc2 += p[2]; sacc3 += p[3];
        }
    }
    __shared__ float sblk[4];
    if (tid < 4) sblk[tid] = 0.f;
    __syncthreads();
    if (j == 0) {
        atomicAdd(&sblk[0], sacc0);
        atomicAdd(&sblk[1], sacc1);
        atomicAdd(&sblk[2], sacc2);
        atomicAdd(&sblk[3], sacc3);
    }
    __syncthreads();
    if (tid < 4) atomicAdd(&S[tid], (double)sblk[tid]);
}

// ---------------------------------------------------------------------------
// aggregate: per-node (16 lanes/node). Gather Vp[src] (1 KB), weight by
// normalized p, accumulate in registers, single non-atomic write + bias.
// ---------------------------------------------------------------------------
__global__ __launch_bounds__(256) void aggregate_kernel(const float* __restrict__ Vp,
                                                        const float* __restrict__ P,
                                                        const int* __restrict__ rp,
                                                        const int* __restrict__ cnt,
                                                        const int2* __restrict__ payload,
                                                        const double* __restrict__ S,
                                                        const float* __restrict__ b_out,
                                                        float* __restrict__ out) {
    const int tid = threadIdx.x;
    const int j = tid & 15;
    const int node = blockIdx.x * 16 + (tid >> 4);

    __shared__ float invs[4];
    if (tid < 4) invs[tid] = (float)(1.0 / S[tid]);
    __syncthreads();

    float4 acc0 = make_float4(0.f, 0.f, 0.f, 0.f);
    float4 acc1 = acc0, acc2 = acc0, acc3 = acc0;
    const int start = rp[node];
    const int end = cnt[node];
    for (int e = start; e < end; ++e) {
        int2 pl = payload[e];
        const int s = pl.x;
        const float4 p4 = *(const float4*)(P + (size_t)e * 4);
        const float4* vr = (const float4*)(Vp + (size_t)s * D);
        float4 v0 = vr[j], v1 = vr[16 + j], v2 = vr[32 + j], v3 = vr[48 + j];
        acc0.x += p4.x * v0.x; acc0.y += p4.x * v0.y; acc0.z += p4.x * v0.z; acc0.w += p4.x * v0.w;
        acc1.x += p4.y * v1.x; acc1.y += p4.y * v1.y; acc1.z += p4.y * v1.z; acc1.w += p4.y * v1.w;
        acc2.x += p4.z * v2.x; acc2.y += p4.z * v2.y; acc2.z += p4.z * v2.z; acc2.w += p4.z * v2.w;
        acc3.x += p4.w * v3.x; acc3.y += p4.w * v3.y; acc3.z += p4.w * v3.z; acc3.w += p4.w * v3.w;
    }
    const float i0 = invs[0], i1 = invs[1], i2 = invs[2], i3 = invs[3];
    const float4 b4 = *(const float4*)(b_out + j * 4);
    float4 r;
    r.x = b4.x + i0 * acc0.x + i1 * acc1.x + i2 * acc2.x + i3 * acc3.x;
    r.y = b4.y + i0 * acc0.y + i1 * acc1.y + i2 * acc2.y + i3 * acc3.y;
    r.z = b4.z + i0 * acc0.z + i1 * acc1.z + i2 * acc2.z + i3 * acc3.z;
    r.w = b4.w + i0 * acc0.w + i1 * acc1.w + i2 * acc2.w + i3 * acc3.w;
    *(float4*)(out + (size_t)node * OUT_CH + j * 4) = r;
}

// ---------------------------------------------------------------------------
// Launch
// ---------------------------------------------------------------------------
extern "C" void kernel_launch(void* const* d_in, const int* in_sizes, int n_in,
                              void* d_out, int out_size, void* d_ws, size_t ws_size,
                              hipStream_t stream) {
    const float* x     = (const float*)d_in[0];
    const int*   ei    = (const int*)d_in[1];   // [2, E] int32
    const float* ew    = (const float*)d_in[2];
    const float* Wq    = (const float*)d_in[3];
    const float* Wk    = (const float*)d_in[4];
    const float* Wv    = (const float*)d_in[5];
    const float* We    = (const float*)d_in[6];
    const float* Wout  = (const float*)d_in[7];
    const float* b_out = (const float*)d_in[8];
    float* out = (float*)d_out;

    // workspace layout (~167 MB)
    float*  u    = (float*)d_ws;                         // 50000*512 = 102.4 MB
    float*  Vp   = u + (size_t)N_NODES * UDIM;           // 50000*256 = 51.2 MB
    float*  P    = Vp + (size_t)N_NODES * D;             // 500000*4  = 8 MB
    double* S    = (double*)(P + (size_t)N_EDGES * HEADS);  // 4 doubles
    float*  M    = (float*)(S + HEADS);                  // 128*512
    float*  Z    = M + IN_CH * UDIM;                     // 128*256
    int*    rp   = (int*)(Z + IN_CH * D);                // 50000
    int*    cnt  = rp + N_NODES;                         // 50000
    int*    csum = cnt + N_NODES;                        // 64
    int2*   payload = (int2*)(csum + 64);                // 500000*8 = 4 MB

    init_kernel<<<(N_NODES + 255) / 256, 256, 0, stream>>>(cnt, S);
    mbuild_kernel<<<HEADS, 256, 0, stream>>>(Wq, Wk, M);
    zbuild_kernel<<<HEADS, 256, 0, stream>>>(Wv, Wout, Z);
    gemm_kernel<<<dim3((N_NODES + 127) / 128, 6), 256, 0, stream>>>(x, M, Z, u, Vp);
    hist_kernel<<<(N_EDGES + 255) / 256, 256, 0, stream>>>(ei, cnt);
    scan_reduce_kernel<<<NC, 256, 0, stream>>>(cnt, csum);
    scan_top_kernel<<<1, 64, 0, stream>>>(csum);
    scan_chunks_kernel<<<NC, 256, 0, stream>>>(cnt, csum, rp);
    scatter_kernel<<<(N_EDGES + 255) / 256, 256, 0, stream>>>(ei, ew, cnt, payload);
    logits_kernel<<<N_NODES / 16, 256, 0, stream>>>(u, x, rp, cnt, payload, We, P, S);
    aggregate_kernel<<<N_NODES / 16, 256, 0, stream>>>(Vp, P, rp, cnt, payload, S, b_out, out);
}

// Round 4
// 586.223 us; speedup vs baseline: 2.2118x; 1.1220x over previous
//
#include <hip/hip_runtime.h>
#include <hip/hip_bf16.h>

// Problem constants
#define N_NODES 50000
#define N_EDGES 500000
#define IN_CH   128
#define D       256   // HEADS * OUT_CH
#define UDIM    512   // HEADS * 128 (u and y width)
#define OUT_CH  64
#define HEADS   4
#define NC      49    // scan chunks of 1024: ceil(50000/1024)

// ---------------------------------------------------------------------------
// init: zero histogram counters and softmax denominators
// ---------------------------------------------------------------------------
__global__ __launch_bounds__(256) void init_kernel(int* __restrict__ cnt,
                                                   double* __restrict__ S) {
    int i = blockIdx.x * 256 + threadIdx.x;
    if (i < N_NODES) cnt[i] = 0;
    if (i < HEADS) S[i] = 0.0;
}

// ---------------------------------------------------------------------------
// M[i][h*128+j] = sum_c Wq[i][h*64+c] * Wk[j][h*64+c]   (one block per head)
// ---------------------------------------------------------------------------
__global__ __launch_bounds__(256) void mbuild_kernel(const float* __restrict__ Wq,
                                                     const float* __restrict__ Wk,
                                                     float* __restrict__ M) {
    const int h = blockIdx.x;
    const int tid = threadIdx.x;
    __shared__ float ks[128][64];
    for (int i = tid; i < 128 * 64; i += 256) {
        int r = i >> 6, c = i & 63;
        ks[r][c] = Wk[(size_t)r * D + h * 64 + c];
    }
    __syncthreads();
    const int i = tid >> 1;
    const int j0 = (tid & 1) * 64;
    float q[64];
    #pragma unroll 16
    for (int c = 0; c < 64; ++c) q[c] = Wq[(size_t)i * D + h * 64 + c];
    for (int jj = 0; jj < 64; ++jj) {
        int j = j0 + jj;
        float s = 0.f;
        #pragma unroll 16
        for (int c = 0; c < 64; ++c) s += q[c] * ks[j][c];
        M[(size_t)i * UDIM + h * 128 + j] = s;
    }
}

// ---------------------------------------------------------------------------
// Zc[(h*128+i)*64 + c] = sum_j Wv[i][h*64+j] * Wout[(h*64+j)][c]
// (x-space -> out-space per-head matrix, stacked [512,64])
// ---------------------------------------------------------------------------
__global__ __launch_bounds__(256) void zbuild_kernel(const float* __restrict__ Wv,
                                                     const float* __restrict__ Wout,
                                                     float* __restrict__ Zc) {
    int h = blockIdx.x;
    int tid = threadIdx.x;
    __shared__ float wo[64 * 64];
    for (int i = tid; i < 64 * 64; i += 256) {
        int j = i >> 6, c = i & 63;
        wo[i] = Wout[(h * 64 + j) * OUT_CH + c];
    }
    __syncthreads();
    int c = tid & 63, i0 = tid >> 6;
    for (int i = i0; i < IN_CH; i += 4) {
        float s = 0.f;
        const float* wv = Wv + (size_t)i * D + h * 64;
        #pragma unroll 8
        for (int j = 0; j < 64; ++j) s += wv[j] * wo[j * 64 + c];
        Zc[(size_t)(h * 128 + i) * OUT_CH + c] = s;
    }
}

// ---------------------------------------------------------------------------
// GEMM1: u = x[50000x128] @ M[128x512].  BM=BN=128, BK=32, 8x8 microtile.
// As XOR-swizzled: element (k,m) at As[k][m ^ (k & 28)] -> conflict-free
// transpose writes (2-way) and float4-aligned broadcast reads.
// ---------------------------------------------------------------------------
__global__ __launch_bounds__(256) void gemm_u_kernel(const float* __restrict__ x,
                                                     const float* __restrict__ M,
                                                     float* __restrict__ u) {
    __shared__ float As[32][128];
    __shared__ float Bs[32][128];

    const int bm = blockIdx.x;
    const int colbase = blockIdx.y * 128;   // 0..3
    const int m0 = bm * 128;
    const int tid = threadIdx.x;
    const int tx = tid & 15, ty = tid >> 4;

    float acc[8][8];
    #pragma unroll
    for (int i = 0; i < 8; ++i)
        #pragma unroll
        for (int j = 0; j < 8; ++j) acc[i][j] = 0.f;

    for (int kt = 0; kt < 4; ++kt) {
        const int k0 = kt * 32;
        #pragma unroll
        for (int r = 0; r < 4; ++r) {
            int f = tid + r * 256;
            int m = f >> 3, k4 = (f & 7) << 2;
            float4 v = make_float4(0.f, 0.f, 0.f, 0.f);
            if (m0 + m < N_NODES)
                v = *(const float4*)(x + (size_t)(m0 + m) * IN_CH + k0 + k4);
            const int sc = m ^ k4;          // XOR swizzle
            As[k4 + 0][sc] = v.x; As[k4 + 1][sc] = v.y;
            As[k4 + 2][sc] = v.z; As[k4 + 3][sc] = v.w;
        }
        #pragma unroll
        for (int r = 0; r < 4; ++r) {
            int f = tid + r * 256;
            int kb = f >> 5, n4 = (f & 31) << 2;
            *(float4*)&Bs[kb][n4] = *(const float4*)(M + (size_t)(k0 + kb) * UDIM + colbase + n4);
        }
        __syncthreads();
        #pragma unroll
        for (int kk = 0; kk < 32; ++kk) {
            const int sw = kk & 28;
            float a[8], b[8];
            *(float4*)(a)     = *(float4*)&As[kk][(ty * 4) ^ sw];
            *(float4*)(a + 4) = *(float4*)&As[kk][(64 + ty * 4) ^ sw];
            *(float4*)(b)     = *(float4*)&Bs[kk][tx * 4];
            *(float4*)(b + 4) = *(float4*)&Bs[kk][64 + tx * 4];
            #pragma unroll
            for (int i = 0; i < 8; ++i)
                #pragma unroll
                for (int j = 0; j < 8; ++j)
                    acc[i][j] += a[i] * b[j];
        }
        __syncthreads();
    }
    #pragma unroll
    for (int i = 0; i < 8; ++i) {
        int row = (i < 4) ? (ty * 4 + i) : (64 + ty * 4 + (i - 4));
        int m = m0 + row;
        if (m < N_NODES) {
            float* dst = u + (size_t)m * UDIM + colbase;
            *(float4*)(dst + tx * 4)      = *(float4*)&acc[i][0];
            *(float4*)(dst + 64 + tx * 4) = *(float4*)&acc[i][4];
        }
    }
}

// ---------------------------------------------------------------------------
// counting sort by tgt: histogram -> 3-phase scan -> scatter payload {src,w}
// ---------------------------------------------------------------------------
__global__ __launch_bounds__(256) void hist_kernel(const int* __restrict__ ei,
                                                   int* __restrict__ cnt) {
    int e = blockIdx.x * 256 + threadIdx.x;
    if (e < N_EDGES) atomicAdd(&cnt[ei[N_EDGES + e]], 1);
}

__global__ __launch_bounds__(256) void scan_reduce_kernel(const int* __restrict__ cnt,
                                                          int* __restrict__ csum) {
    const int b = blockIdx.x, tid = threadIdx.x;
    const int lane = tid & 63, wid = tid >> 6;
    int s = 0;
    int idx0 = b * 1024 + tid * 4;
    #pragma unroll
    for (int i = 0; i < 4; ++i) {
        int idx = idx0 + i;
        if (idx < N_NODES) s += cnt[idx];
    }
    #pragma unroll
    for (int m = 1; m < 64; m <<= 1) s += __shfl_xor(s, m, 64);
    __shared__ int w[4];
    if (lane == 0) w[wid] = s;
    __syncthreads();
    if (tid == 0) csum[b] = w[0] + w[1] + w[2] + w[3];
}

__global__ __launch_bounds__(64) void scan_top_kernel(int* __restrict__ csum) {
    int lane = threadIdx.x;
    int v = (lane < NC) ? csum[lane] : 0;
    int x = v;
    #pragma unroll
    for (int d = 1; d < 64; d <<= 1) {
        int y = __shfl_up(x, d, 64);
        if (lane >= d) x += y;
    }
    if (lane < NC) csum[lane] = x - v;   // exclusive
}

__global__ __launch_bounds__(256) void scan_chunks_kernel(int* __restrict__ cnt,
                                                          const int* __restrict__ csum,
                                                          int* __restrict__ rp) {
    const int b = blockIdx.x, tid = threadIdx.x;
    const int lane = tid & 63, wid = tid >> 6;
    __shared__ int wsum[4];
    int v[4];
    const int idx0 = b * 1024 + tid * 4;
    #pragma unroll
    for (int i = 0; i < 4; ++i) {
        int idx = idx0 + i;
        v[i] = (idx < N_NODES) ? cnt[idx] : 0;
    }
    int tsum = v[0] + v[1] + v[2] + v[3];
    int x = tsum;
    #pragma unroll
    for (int d = 1; d < 64; d <<= 1) {
        int y = __shfl_up(x, d, 64);
        if (lane >= d) x += y;
    }
    if (lane == 63) wsum[wid] = x;
    __syncthreads();
    int woff = 0;
    for (int w = 0; w < wid; ++w) woff += wsum[w];
    int excl = csum[b] + woff + x - tsum;
    #pragma unroll
    for (int i = 0; i < 4; ++i) {
        int idx = idx0 + i;
        if (idx < N_NODES) { rp[idx] = excl; cnt[idx] = excl; }
        excl += v[i];
    }
}

__global__ __launch_bounds__(256) void scatter_kernel(const int* __restrict__ ei,
                                                      const float* __restrict__ ew,
                                                      int* __restrict__ cnt,
                                                      int2* __restrict__ payload) {
    int e = blockIdx.x * 256 + threadIdx.x;
    if (e >= N_EDGES) return;
    int s = ei[e], t = ei[N_EDGES + e];
    int pos = atomicAdd(&cnt[t], 1);
    payload[pos] = make_int2(s, __float_as_int(ew[e]));
}

// ---------------------------------------------------------------------------
// Fused edge kernel: per tgt node (16 lanes), loop incoming edges:
//   gather x_s (512 B, once), d_h = u_t . x_s (shfl-16), p = exp(leaky(...)),
//   y_h += p_h * x_s  (registers). Write y over u[node] in place.
//   Accumulate S[h] (double). No P array, no Vp, no atomics on out.
// ---------------------------------------------------------------------------
__global__ __launch_bounds__(256) void edge_fused_kernel(float* __restrict__ u,
                                                         const float* __restrict__ x,
                                                         const int* __restrict__ rp,
                                                         const int* __restrict__ cnt,
                                                         const int2* __restrict__ payload,
                                                         const float* __restrict__ We,
                                                         double* __restrict__ S) {
    const int tid = threadIdx.x;
    const int j = tid & 15;
    const int node = blockIdx.x * 16 + (tid >> 4);
    const float4 we = *(const float4*)We;
    const float wev[4] = {we.x, we.y, we.z, we.w};

    // u[node] fragment: lane j holds, per head h, floats [h*128 + j*8 .. +7]
    float4* ur = (float4*)(u + (size_t)node * UDIM);
    float4 ua[4], ub[4], ya[4], yb[4];
    #pragma unroll
    for (int h = 0; h < 4; ++h) {
        ua[h] = ur[h * 32 + j * 2];
        ub[h] = ur[h * 32 + j * 2 + 1];
        ya[h] = make_float4(0.f, 0.f, 0.f, 0.f);
        yb[h] = make_float4(0.f, 0.f, 0.f, 0.f);
    }

    float sacc[4] = {0.f, 0.f, 0.f, 0.f};
    const int start = rp[node];
    const int end = cnt[node];
    for (int e = start; e < end; ++e) {
        int2 pl = payload[e];
        const int s = pl.x;
        const float w = __int_as_float(pl.y);
        const float4* xr = (const float4*)(x + (size_t)s * IN_CH);
        float4 xa = xr[j * 2], xb = xr[j * 2 + 1];
        float d[4];
        #pragma unroll
        for (int h = 0; h < 4; ++h) {
            d[h] = ua[h].x * xa.x + ua[h].y * xa.y + ua[h].z * xa.z + ua[h].w * xa.w
                 + ub[h].x * xb.x + ub[h].y * xb.y + ub[h].z * xb.z + ub[h].w * xb.w;
        }
        #pragma unroll
        for (int m = 1; m < 16; m <<= 1) {
            #pragma unroll
            for (int h = 0; h < 4; ++h) d[h] += __shfl_xor(d[h], m, 16);
        }
        float p[4];
        #pragma unroll
        for (int h = 0; h < 4; ++h) {
            float l = d[h] * 0.125f + w * wev[h];
            l = (l > 0.f) ? l : 0.2f * l;
            p[h] = __expf(l);
        }
        #pragma unroll
        for (int h = 0; h < 4; ++h) {
            ya[h].x += p[h] * xa.x; ya[h].y += p[h] * xa.y;
            ya[h].z += p[h] * xa.z; ya[h].w += p[h] * xa.w;
            yb[h].x += p[h] * xb.x; yb[h].y += p[h] * xb.y;
            yb[h].z += p[h] * xb.z; yb[h].w += p[h] * xb.w;
        }
        if (j == 0) {
            sacc[0] += p[0]; sacc[1] += p[1]; sacc[2] += p[2]; sacc[3] += p[3];
        }
    }
    // write y over u[node] (this thread's own fragment; u no longer needed)
    #pragma unroll
    for (int h = 0; h < 4; ++h) {
        ur[h * 32 + j * 2]     = ya[h];
        ur[h * 32 + j * 2 + 1] = yb[h];
    }
    __shared__ float sblk[4];
    if (tid < 4) sblk[tid] = 0.f;
    __syncthreads();
    if (j == 0) {
        atomicAdd(&sblk[0], sacc[0]);
        atomicAdd(&sblk[1], sacc[1]);
        atomicAdd(&sblk[2], sacc[2]);
        atomicAdd(&sblk[3], sacc[3]);
    }
    __syncthreads();
    if (tid < 4) atomicAdd(&S[tid], (double)sblk[tid]);
}

// ---------------------------------------------------------------------------
// GEMM2: out = (y scaled by 1/S per head) @ Zc[512,64] + b_out
// BM=128, BN=64, BK=32, 256 thr, 8x4 microtile. 1/S folded into Bs staging.
// ---------------------------------------------------------------------------
__global__ __launch_bounds__(256) void gemm_out_kernel(const float* __restrict__ y,
                                                       const float* __restrict__ Zc,
                                                       const double* __restrict__ S,
                                                       const float* __restrict__ b_out,
                                                       float* __restrict__ out) {
    __shared__ float As[32][128];
    __shared__ float Bs[32][64];
    __shared__ float invs[4];

    const int m0 = blockIdx.x * 128;
    const int tid = threadIdx.x;
    const int tx = tid & 15, ty = tid >> 4;

    if (tid < 4) invs[tid] = (float)(1.0 / S[tid]);
    __syncthreads();

    float acc[8][4];
    #pragma unroll
    for (int i = 0; i < 8; ++i)
        #pragma unroll
        for (int jj = 0; jj < 4; ++jj) acc[i][jj] = 0.f;

    for (int kt = 0; kt < 16; ++kt) {
        const int k0 = kt * 32;
        #pragma unroll
        for (int r = 0; r < 4; ++r) {
            int f = tid + r * 256;
            int m = f >> 3, k4 = (f & 7) << 2;
            float4 v = make_float4(0.f, 0.f, 0.f, 0.f);
            if (m0 + m < N_NODES)
                v = *(const float4*)(y + (size_t)(m0 + m) * UDIM + k0 + k4);
            const int sc = m ^ k4;
            As[k4 + 0][sc] = v.x; As[k4 + 1][sc] = v.y;
            As[k4 + 2][sc] = v.z; As[k4 + 3][sc] = v.w;
        }
        {   // Bs: 32x64 floats = 2 float4/thread; scale by invs[head]
            const float sc0 = invs[k0 >> 7];   // whole 32-k tile is one head
            #pragma unroll
            for (int r = 0; r < 2; ++r) {
                int f = tid + r * 256;
                int kb = f >> 4, n4 = (f & 15) << 2;
                float4 v = *(const float4*)(Zc + (size_t)(k0 + kb) * OUT_CH + n4);
                v.x *= sc0; v.y *= sc0; v.z *= sc0; v.w *= sc0;
                *(float4*)&Bs[kb][n4] = v;
            }
        }
        __syncthreads();
        #pragma unroll
        for (int kk = 0; kk < 32; ++kk) {
            const int sw = kk & 28;
            float a[8], b[4];
            *(float4*)(a)     = *(float4*)&As[kk][(ty * 4) ^ sw];
            *(float4*)(a + 4) = *(float4*)&As[kk][(64 + ty * 4) ^ sw];
            *(float4*)(b)     = *(float4*)&Bs[kk][tx * 4];
            #pragma unroll
            for (int i = 0; i < 8; ++i)
                #pragma unroll
                for (int jj = 0; jj < 4; ++jj)
                    acc[i][jj] += a[i] * b[jj];
        }
        __syncthreads();
    }
    const float4 b4 = *(const float4*)(b_out + tx * 4);
    #pragma unroll
    for (int i = 0; i < 8; ++i) {
        int row = (i < 4) ? (ty * 4 + i) : (64 + ty * 4 + (i - 4));
        int m = m0 + row;
        if (m < N_NODES) {
            float4 r = *(float4*)&acc[i][0];
            r.x += b4.x; r.y += b4.y; r.z += b4.z; r.w += b4.w;
            *(float4*)(out + (size_t)m * OUT_CH + tx * 4) = r;
        }
    }
}

// ---------------------------------------------------------------------------
// Launch
// ---------------------------------------------------------------------------
extern "C" void kernel_launch(void* const* d_in, const int* in_sizes, int n_in,
                              void* d_out, int out_size, void* d_ws, size_t ws_size,
                              hipStream_t stream) {
    const float* x     = (const float*)d_in[0];
    const int*   ei    = (const int*)d_in[1];   // [2, E] int32
    const float* ew    = (const float*)d_in[2];
    const float* Wq    = (const float*)d_in[3];
    const float* Wk    = (const float*)d_in[4];
    const float* Wv    = (const float*)d_in[5];
    const float* We    = (const float*)d_in[6];
    const float* Wout  = (const float*)d_in[7];
    const float* b_out = (const float*)d_in[8];
    float* out = (float*)d_out;

    // workspace layout (~107 MB)
    float*  u    = (float*)d_ws;                         // 50000*512 = 102.4 MB (u, then y in place)
    double* S    = (double*)(u + (size_t)N_NODES * UDIM);
    float*  M    = (float*)(S + HEADS);                  // 128*512
    float*  Zc   = M + IN_CH * UDIM;                     // 512*64
    int*    rp   = (int*)(Zc + UDIM * OUT_CH);           // 50000
    int*    cnt  = rp + N_NODES;                         // 50000
    int*    csum = cnt + N_NODES;                        // 64
    int2*   payload = (int2*)(csum + 64);                // 500000*8 = 4 MB

    init_kernel<<<(N_NODES + 255) / 256, 256, 0, stream>>>(cnt, S);
    mbuild_kernel<<<HEADS, 256, 0, stream>>>(Wq, Wk, M);
    zbuild_kernel<<<HEADS, 256, 0, stream>>>(Wv, Wout, Zc);
    gemm_u_kernel<<<dim3((N_NODES + 127) / 128, 4), 256, 0, stream>>>(x, M, u);
    hist_kernel<<<(N_EDGES + 255) / 256, 256, 0, stream>>>(ei, cnt);
    scan_reduce_kernel<<<NC, 256, 0, stream>>>(cnt, csum);
    scan_top_kernel<<<1, 64, 0, stream>>>(csum);
    scan_chunks_kernel<<<NC, 256, 0, stream>>>(cnt, csum, rp);
    scatter_kernel<<<(N_EDGES + 255) / 256, 256, 0, stream>>>(ei, ew, cnt, payload);
    edge_fused_kernel<<<N_NODES / 16, 256, 0, stream>>>(u, x, rp, cnt, payload, We, S);
    gemm_out_kernel<<<(N_NODES + 127) / 128, 256, 0, stream>>>(u, Zc, S, b_out, out);
}